// Round 9
// baseline (210.057 us; speedup 1.0000x reference)
//
#include <hip/hip_runtime.h>

#define B_  8
#define C_  256
#define C2_ 128
#define N_  4096
#define LOG2E 1.44269504088896f

typedef _Float16 f16;
typedef _Float16 f16x8 __attribute__((ext_vector_type(8)));
typedef float f32x4  __attribute__((ext_vector_type(4)));

static __device__ __forceinline__ unsigned pk2(float a, float b) {
  return __builtin_bit_cast(unsigned, __builtin_amdgcn_cvt_pkrtz(a, b));  // v_cvt_pkrtz_f16_f32
}

// quad-row swap: r0 = {a.q0, b.q0, a.q2, b.q2}, r1 = {a.q1, b.q1, a.q3, b.q3}
static __device__ __forceinline__ void plane16_swap(unsigned a, unsigned b,
                                                    unsigned& r0, unsigned& r1) {
#if __has_builtin(__builtin_amdgcn_permlane16_swap)
  auto r = __builtin_amdgcn_permlane16_swap(a, b, false, false);
  r0 = (unsigned)r[0]; r1 = (unsigned)r[1];
#else
  asm volatile("v_permlane16_swap_b32 %0, %1" : "+v"(a), "+v"(b));
  r0 = a; r1 = b;
#endif
}

// direct global->LDS 16B copy: per-lane global src, wave-uniform LDS base + lane*16
static __device__ __forceinline__ void gload16(const void* g, void* l) {
  __builtin_amdgcn_global_load_lds(
      (const __attribute__((address_space(1))) unsigned int*)g,
      (__attribute__((address_space(3))) unsigned int*)l, 16, 0, 0);
}

// ---------------------------------------------------------------------------
// prep: cast W1/W2 to f16 once (32768 elements each)
// ---------------------------------------------------------------------------
__global__ __launch_bounds__(256)
void prep_kernel(const float* __restrict__ W1, const float* __restrict__ W2,
                 f16* __restrict__ w1h, f16* __restrict__ w2h)
{
  int i = blockIdx.x * 256 + threadIdx.x;   // grid 128 -> 32768
  w1h[i] = (f16)W1[i];
  w2h[i] = (f16)W2[i];
}

// ---------------------------------------------------------------------------
// conv1: Y[b,n,c2] = sum_c x[b,c,n]*W1[c2,c] + b1; dual layout Y + Yt.
// (unchanged from verified baseline)
// ---------------------------------------------------------------------------
__global__ __launch_bounds__(256, 3)
void conv1_kernel(const float* __restrict__ x,
                  const f16* __restrict__ w1h,
                  const float* __restrict__ b1,
                  f16* __restrict__ Y, f16* __restrict__ Yt)
{
  __shared__ __align__(16) char smem[49152];
  float* Xr = (float*)smem;            // [256 c][32 n] f32, float4-block XOR (32 KB)
  f16*   Ah = (f16*)(smem + 32768);    // [32 n][256 k] f16 XOR-8 (16 KB)
  f16*   T  = (f16*)smem;              // [128 c2][40 n] epilogue alias

  const int t = threadIdx.x;
  const int w = t >> 6, lane = t & 63, quad = lane >> 4, l16 = lane & 15;
  const int b = blockIdx.x, nt0 = blockIdx.y;

  // stage all 256c x 32n fp32 (8 outstanding float4 loads)
#pragma unroll
  for (int pass = 0; pass < 8; pass++) {
    int c  = (t >> 3) + pass * 32;            // 0..255
    int n4 = t & 7;
    float4 v = *(const float4*)(x + ((long)(b * C_ + c)) * N_ + nt0 * 32 + n4 * 4);
    *(float4*)(&Xr[c * 32 + (n4 ^ (c & 7)) * 4]) = v;
  }
  __syncthreads();
  // transpose+cvt into Ah [n][k] XOR-8
#pragma unroll
  for (int pass = 0; pass < 4; pass++) {
    int n  = t & 31;
    int kb = (t >> 5) + pass * 8;             // 0..31
    f16x8 vh;
#pragma unroll
    for (int jj = 0; jj < 8; jj++) {
      int cc = kb * 8 + jj;
      vh[jj] = (f16)Xr[cc * 32 + ((n >> 2) ^ (cc & 7)) * 4 + (n & 3)];
    }
    *(f16x8*)(&Ah[n * 256 + (kb ^ (n & 7)) * 8]) = vh;
  }
  __syncthreads();

  // B-frags from global (L2-hot, shared by all WGs)
  f16x8 bh[2][8];
#pragma unroll
  for (int nt = 0; nt < 2; nt++) {
    int c2 = w * 32 + nt * 16 + l16;
#pragma unroll
    for (int ks = 0; ks < 8; ks++)
      bh[nt][ks] = *(const f16x8*)(w1h + c2 * C_ + ks * 32 + quad * 8);
  }

  f32x4 acc[2][2];
#pragma unroll
  for (int i = 0; i < 2; i++)
#pragma unroll
    for (int j = 0; j < 2; j++) acc[i][j] = (f32x4){0.f, 0.f, 0.f, 0.f};

#pragma unroll
  for (int ks = 0; ks < 8; ks++)
#pragma unroll
    for (int mt = 0; mt < 2; mt++) {
      f16x8 ah = *(const f16x8*)(&Ah[(mt * 16 + l16) * 256 + (((ks * 4 + quad) ^ (l16 & 7))) * 8]);
#pragma unroll
      for (int nt = 0; nt < 2; nt++)
        acc[mt][nt] = __builtin_amdgcn_mfma_f32_16x16x32_f16(ah, bh[nt][ks], acc[mt][nt], 0, 0, 0);
    }
  __syncthreads();   // Xr dead -> T alias safe

  // epilogue -> T[c2][n]
#pragma unroll
  for (int nt = 0; nt < 2; nt++) {
    int c2 = w * 32 + nt * 16 + l16;
    float bv = b1[c2];
#pragma unroll
    for (int mt = 0; mt < 2; mt++)
#pragma unroll
      for (int rg = 0; rg < 4; rg++) {
        int n = mt * 16 + quad * 4 + rg;
        T[c2 * 40 + n] = (f16)(acc[mt][nt][rg] + bv);
      }
  }
  __syncthreads();
  // Yt[c2][n]: vec8 along n
#pragma unroll
  for (int pass = 0; pass < 2; pass++) {
    int r  = (t >> 2) + pass * 64;            // c2 0..127
    int c8 = (t & 3) * 8;                     // n
    f16x8 v = *(const f16x8*)(&T[r * 40 + c8]);
    *(f16x8*)(Yt + ((long)(b * C2_ + r)) * N_ + nt0 * 32 + c8) = v;
  }
  // Y[n][c2]: gather
#pragma unroll
  for (int pass = 0; pass < 2; pass++) {
    int row = t & 31;
    int cg  = (t >> 5) + pass * 8;            // c2-block 0..15
    f16x8 v;
#pragma unroll
    for (int jj = 0; jj < 8; jj++) v[jj] = T[(cg * 8 + jj) * 40 + row];
    *(f16x8*)(Y + ((long)(b * N_ + nt0 * 32 + row)) * C2_ + cg * 8) = v;
  }
}

// ---------------------------------------------------------------------------
// attn v9: R8 compute body (swapped QK^T, register P via permlane32+permlane16,
// conflict-free 16x16x32 PV) with DIRECT global->LDS staging:
//   - double-buffered Ks/Vs; per tile each wave issues 8 global_load_lds
//     (4 K-chunks + 4 V-chunks of 1 KB: wave-uniform LDS base + lane*16),
//     issued at the TOP of the body so the whole compute phase hides the
//     (L2-resident, ~200cy) latency; ONE __syncthreads per tile (its vmcnt
//     drain is free by then).
//   - swizzle via rule #21: LINEAR LDS dest + inverse-swizzled per-lane
//     GLOBAL source (per-row block permutation -> coalescing preserved).
//   - removes 8 ds_write_b128/wave/tile from the DS pipe (~20% of its
//     traffic), the staging VALU, and 32 prefetch VGPRs.
// launch_bounds(256,2): do NOT tighten (R4: forced 64 VGPR = 717 MB spill).
// ---------------------------------------------------------------------------
__global__ __launch_bounds__(256, 2)
void attn_kernel(const f16* __restrict__ Y, const f16* __restrict__ Yt,
                 f16* __restrict__ Op, float* __restrict__ ls)
{
  __shared__ f16 Ks[2][64 * 128];   // [key][d]  16B-block pos = (d>>3) ^ (key&15)
  __shared__ f16 Vs[2][128 * 64];   // [d][k]    pos = (k>>3) ^ (d&7)
  __shared__ float nsqf[128];

  const int t = threadIdx.x;
  const int w = t >> 6, lane = t & 63, quad = lane >> 4, l16 = lane & 15;
  const int b = blockIdx.x, qt = blockIdx.y, s = blockIdx.z;
  const int ns = gridDim.z;
  const f16* Yb  = Y  + (long)b * N_ * C2_;
  const f16* Ytb = Yt + (long)b * C2_ * N_;
  const int g0 = (s * 64) / ns;        // first 64-key tile of this split
  const int g1 = ((s + 1) * 64) / ns;  // one past last

  // per-lane global source offsets (f16 units) for the 4 K / 4 V chunks this
  // wave stages. Chunk p of a tile = LDS bytes [p*1024,(p+1)*1024); lane l
  // deposits at byte p*1024 + l*16. K: row r=4p+(l>>4), LDS blk l&15 must hold
  // global d-block (l&15)^(r&15). V: row d=8p+(l>>3), blk l&7 holds k-block
  // (l&7)^(d&7).
  int koff[4], voff[4];
#pragma unroll
  for (int i = 0; i < 4; i++) {
    int p = w + 4 * i;
    int r = 4 * p + (lane >> 4);
    koff[i] = r * C2_ + ((l16 ^ (r & 15)) * 8);
    int d = 8 * p + (lane >> 3);
    voff[i] = d * N_ + (((lane & 7) ^ (d & 7)) * 8);
  }

  // Q frags (A/B-frag layout identical for 16x16x32): row q=l16, d-chunk quad*8
  f16x8 qf[2][4];
#pragma unroll
  for (int mt = 0; mt < 2; mt++)
#pragma unroll
    for (int ks = 0; ks < 4; ks++)
      qf[mt][ks] = *(const f16x8*)(Yb + (long)(qt * 128 + w * 32 + mt * 16 + l16) * C2_ + ks * 32 + quad * 8);

  // per-row |y_q|^2 (exact same f16 values the MFMA sees)
  {
    int r = t >> 1, half = t & 1;
    float ss = 0.f;
#pragma unroll
    for (int j = 0; j < 8; j++) {
      f16x8 v = *(const f16x8*)(Yb + (long)(qt * 128 + r) * C2_ + half * 64 + j * 8);
#pragma unroll
      for (int e = 0; e < 8; e++) { float f = (float)v[e]; ss = fmaf(f, f, ss); }
    }
    ss += __shfl_xor(ss, 1);
    if (!half) nsqf[r] = ss;
  }

  // prologue: stage first tile of this split into buffer 0 (direct to LDS)
  {
    const int kb0 = g0 * 64;
    const f16* gk = Yb + (long)kb0 * C2_;
    const f16* gv = Ytb + kb0;
#pragma unroll
    for (int i = 0; i < 4; i++) {
      gload16(gk + koff[i], &Ks[0][(w + 4 * i) * 512]);
      gload16(gv + voff[i], &Vs[0][(w + 4 * i) * 512]);
    }
  }
  __syncthreads();   // drains vmcnt (gload) + lgkm (nsqf write)

  // fixed per-row max (log2 units), per-lane by q=l16
  float nm[2];
  nm[0] = nsqf[w * 32 + l16] * LOG2E;
  nm[1] = nsqf[w * 32 + 16 + l16] * LOG2E;

  f16x8 ones8;
#pragma unroll
  for (int j = 0; j < 8; j++) ones8[j] = (f16)1.0f;

  f32x4 Oa[2][8];                 // C-layout: row q = quad*4+rg, col d = l16
#pragma unroll
  for (int i = 0; i < 2; i++)
#pragma unroll
    for (int j = 0; j < 8; j++) Oa[i][j] = (f32x4){0.f, 0.f, 0.f, 0.f};
  f32x4 lac[2] = {(f32x4){0.f,0.f,0.f,0.f}, (f32x4){0.f,0.f,0.f,0.f}};

  int cur = 0;
#pragma unroll 1
  for (int g = g0; g < g1; g++) {
    // issue next-tile direct global->LDS loads into the other buffer;
    // they complete under this tile's compute (vmcnt drained at the barrier)
    if (g + 1 < g1) {
      int nb = (g + 1) * 64;
      const f16* gk = Yb + (long)nb * C2_;
      const f16* gv = Ytb + nb;
#pragma unroll
      for (int i = 0; i < 4; i++) {
        gload16(gk + koff[i], &Ks[cur ^ 1][(w + 4 * i) * 512]);
        gload16(gv + voff[i], &Vs[cur ^ 1][(w + 4 * i) * 512]);
      }
    }

    // ---- QKT half A: S[0],S[1] (nt=0,1) complete first ----
    f32x4 S[4][2];
#pragma unroll
    for (int i = 0; i < 4; i++)
#pragma unroll
      for (int j = 0; j < 2; j++) S[i][j] = (f32x4){0.f, 0.f, 0.f, 0.f};
#pragma unroll
    for (int ks = 0; ks < 4; ks++) {
      f16x8 b0 = *(const f16x8*)(&Ks[cur][(0 * 16 + l16) * 128 + (((ks * 4 + quad) ^ l16)) * 8]);
      f16x8 b1 = *(const f16x8*)(&Ks[cur][(1 * 16 + l16) * 128 + (((ks * 4 + quad) ^ l16)) * 8]);
      __builtin_amdgcn_s_setprio(1);
#pragma unroll
      for (int mt = 0; mt < 2; mt++) {
        S[0][mt] = __builtin_amdgcn_mfma_f32_16x16x32_f16(b0, qf[mt][ks], S[0][mt], 0, 0, 0);
        S[1][mt] = __builtin_amdgcn_mfma_f32_16x16x32_f16(b1, qf[mt][ks], S[1][mt], 0, 0, 0);
      }
      __builtin_amdgcn_s_setprio(0);
    }
    // ---- QKT half B: S[2],S[3] issue (exp half0 hides under these) ----
#pragma unroll
    for (int ks = 0; ks < 4; ks++) {
      f16x8 b2 = *(const f16x8*)(&Ks[cur][(2 * 16 + l16) * 128 + (((ks * 4 + quad) ^ l16)) * 8]);
      f16x8 b3 = *(const f16x8*)(&Ks[cur][(3 * 16 + l16) * 128 + (((ks * 4 + quad) ^ l16)) * 8]);
      __builtin_amdgcn_s_setprio(1);
#pragma unroll
      for (int mt = 0; mt < 2; mt++) {
        S[2][mt] = __builtin_amdgcn_mfma_f32_16x16x32_f16(b2, qf[mt][ks], S[2][mt], 0, 0, 0);
        S[3][mt] = __builtin_amdgcn_mfma_f32_16x16x32_f16(b3, qf[mt][ks], S[3][mt], 0, 0, 0);
      }
      __builtin_amdgcn_s_setprio(0);
    }

    // ---- exp + exchange half0 (S[0],S[1] -> pa0) ----
    f16x8 pa0[2];
#pragma unroll
    for (int mt = 0; mt < 2; mt++) {
      float n0 = nm[mt];
      unsigned xa0 = pk2(exp2f(fminf(fmaf(S[0][mt][0], LOG2E, -n0), 11.0f)),
                         exp2f(fminf(fmaf(S[0][mt][1], LOG2E, -n0), 11.0f)));
      unsigned xa1 = pk2(exp2f(fminf(fmaf(S[0][mt][2], LOG2E, -n0), 11.0f)),
                         exp2f(fminf(fmaf(S[0][mt][3], LOG2E, -n0), 11.0f)));
      unsigned xb0 = pk2(exp2f(fminf(fmaf(S[1][mt][0], LOG2E, -n0), 11.0f)),
                         exp2f(fminf(fmaf(S[1][mt][1], LOG2E, -n0), 11.0f)));
      unsigned xb1 = pk2(exp2f(fminf(fmaf(S[1][mt][2], LOG2E, -n0), 11.0f)),
                         exp2f(fminf(fmaf(S[1][mt][3], LOG2E, -n0), 11.0f)));
      union { unsigned u[4]; f16x8 v; } P;
      {
        auto c = __builtin_amdgcn_permlane32_swap(xa0, xb0, false, false);
        plane16_swap((unsigned)c[0], (unsigned)c[1], P.u[0], P.u[2]);
      }
      {
        auto c = __builtin_amdgcn_permlane32_swap(xa1, xb1, false, false);
        plane16_swap((unsigned)c[0], (unsigned)c[1], P.u[1], P.u[3]);
      }
      pa0[mt] = P.v;
    }

    // ---- PV0 (ks2=0) ----
    {
      f16x8 vb[8];
#pragma unroll
      for (int dt = 0; dt < 8; dt++)
        vb[dt] = *(const f16x8*)(&Vs[cur][(dt * 16 + l16) * 64 + (((0 * 4 + quad) ^ (l16 & 7))) * 8]);
      __builtin_amdgcn_s_setprio(1);
#pragma unroll
      for (int mt = 0; mt < 2; mt++) {
#pragma unroll
        for (int dt = 0; dt < 8; dt++)
          Oa[mt][dt] = __builtin_amdgcn_mfma_f32_16x16x32_f16(pa0[mt], vb[dt], Oa[mt][dt], 0, 0, 0);
        lac[mt] = __builtin_amdgcn_mfma_f32_16x16x32_f16(pa0[mt], ones8, lac[mt], 0, 0, 0);
      }
      __builtin_amdgcn_s_setprio(0);
    }

    // ---- exp + exchange half1 (S[2],S[3] -> pa1) ----
    f16x8 pa1[2];
#pragma unroll
    for (int mt = 0; mt < 2; mt++) {
      float n0 = nm[mt];
      unsigned xa0 = pk2(exp2f(fminf(fmaf(S[2][mt][0], LOG2E, -n0), 11.0f)),
                         exp2f(fminf(fmaf(S[2][mt][1], LOG2E, -n0), 11.0f)));
      unsigned xa1 = pk2(exp2f(fminf(fmaf(S[2][mt][2], LOG2E, -n0), 11.0f)),
                         exp2f(fminf(fmaf(S[2][mt][3], LOG2E, -n0), 11.0f)));
      unsigned xb0 = pk2(exp2f(fminf(fmaf(S[3][mt][0], LOG2E, -n0), 11.0f)),
                         exp2f(fminf(fmaf(S[3][mt][1], LOG2E, -n0), 11.0f)));
      unsigned xb1 = pk2(exp2f(fminf(fmaf(S[3][mt][2], LOG2E, -n0), 11.0f)),
                         exp2f(fminf(fmaf(S[3][mt][3], LOG2E, -n0), 11.0f)));
      union { unsigned u[4]; f16x8 v; } P;
      {
        auto c = __builtin_amdgcn_permlane32_swap(xa0, xb0, false, false);
        plane16_swap((unsigned)c[0], (unsigned)c[1], P.u[0], P.u[2]);
      }
      {
        auto c = __builtin_amdgcn_permlane32_swap(xa1, xb1, false, false);
        plane16_swap((unsigned)c[0], (unsigned)c[1], P.u[1], P.u[3]);
      }
      pa1[mt] = P.v;
    }

    // ---- PV1 (ks2=1) ----
    {
      f16x8 vb[8];
#pragma unroll
      for (int dt = 0; dt < 8; dt++)
        vb[dt] = *(const f16x8*)(&Vs[cur][(dt * 16 + l16) * 64 + (((1 * 4 + quad) ^ (l16 & 7))) * 8]);
      __builtin_amdgcn_s_setprio(1);
#pragma unroll
      for (int mt = 0; mt < 2; mt++) {
#pragma unroll
        for (int dt = 0; dt < 8; dt++)
          Oa[mt][dt] = __builtin_amdgcn_mfma_f32_16x16x32_f16(pa1[mt], vb[dt], Oa[mt][dt], 0, 0, 0);
        lac[mt] = __builtin_amdgcn_mfma_f32_16x16x32_f16(pa1[mt], ones8, lac[mt], 0, 0, 0);
      }
      __builtin_amdgcn_s_setprio(0);
    }

    __syncthreads();   // all buf[cur] reads done + prefetch gloads drained
    cur ^= 1;
  }

  // epilogue: unnormalized O + row sums l (C-layout: row q, col d)
  const long rbase = ((long)s * B_ + b) * N_ + qt * 128;
#pragma unroll
  for (int mt = 0; mt < 2; mt++)
#pragma unroll
    for (int rg = 0; rg < 4; rg++) {
      int r = w * 32 + mt * 16 + quad * 4 + rg;
#pragma unroll
      for (int dt = 0; dt < 8; dt++)
        Op[(rbase + r) * C2_ + dt * 16 + l16] = (f16)Oa[mt][dt][rg];
      if (l16 == 0) ls[rbase + r] = lac[mt][rg];
    }
}

// ---------------------------------------------------------------------------
// conv2 + fused NS-split-combine + scale + residual. O view [128][4096]/batch;
// within a (j, pt)-tile the source row q = j*32 + (pt>>1) is constant per j,
// so normalization sum_s(Os)/sum_s(ls) folds into the staging pass.
// Grid (8, 64, 2) -> 4 WG/CU.
// ---------------------------------------------------------------------------
__global__ __launch_bounds__(256, 4)
void conv2_kernel(const f16* __restrict__ Op, const float* __restrict__ ls,
                  const f16* __restrict__ w2h,
                  const float* __restrict__ b2,
                  const float* __restrict__ scale,
                  const float* __restrict__ x,
                  float* __restrict__ out, int ns)
{
  __shared__ f16 Or[128 * 72];      // [j][p_local]
  __shared__ f16 Bsw[64 * 128];     // [p][j] XOR-16
  __shared__ float invL[128];

  const int t = threadIdx.x;
  const int w = t >> 6, lane = t & 63, quad = lane >> 4, l16 = lane & 15;
  const int b = blockIdx.x, pt = blockIdx.y, oh = blockIdx.z;
  const long base0 = (long)b * 524288;            // batch offset within a split

  if (t < 128) {
    int q = t * 32 + (pt >> 1);
    float l = 0.f;
    for (int si = 0; si < ns; si++)
      l += ls[(long)si * 32768 + (long)b * N_ + q];
    invL[t] = 1.0f / fmaxf(l, 1e-20f);
  }
  __syncthreads();

#pragma unroll
  for (int pass = 0; pass < 4; pass++) {
    int j = (t >> 3) + pass * 32;            // 0..127
    int c8 = (t & 7) * 8;                    // p_local
    float fa[8] = {0.f,0.f,0.f,0.f,0.f,0.f,0.f,0.f};
    for (int si = 0; si < ns; si++) {
      f16x8 a = *(const f16x8*)(Op + (long)si * 4194304 + base0 + (long)j * N_ + pt * 64 + c8);
#pragma unroll
      for (int jj = 0; jj < 8; jj++) fa[jj] += (float)a[jj];
    }
    float iv = invL[j];
    f16x8 r;
#pragma unroll
    for (int jj = 0; jj < 8; jj++)
      r[jj] = (f16)(fa[jj] * iv);
    *(f16x8*)(&Or[j * 72 + c8]) = r;
  }
  __syncthreads();
#pragma unroll
  for (int pass = 0; pass < 4; pass++) {
    int p = t & 63;
    int q = (t >> 6) + pass * 4;             // j-block 0..15
    f16x8 vv;
#pragma unroll
    for (int jj = 0; jj < 8; jj++) vv[jj] = Or[(q * 8 + jj) * 72 + p];
    *(f16x8*)(&Bsw[p * 128 + ((q ^ (p & 15))) * 8]) = vv;
  }
  __syncthreads();

  f32x4 acc[2][4];
#pragma unroll
  for (int i = 0; i < 2; i++)
#pragma unroll
    for (int j = 0; j < 4; j++) acc[i][j] = (f32x4){0.f, 0.f, 0.f, 0.f};

#pragma unroll
  for (int ks = 0; ks < 4; ks++) {
    f16x8 bfr[4];
#pragma unroll
    for (int nt = 0; nt < 4; nt++)
      bfr[nt] = *(const f16x8*)(&Bsw[(nt * 16 + l16) * 128 + (((ks * 4 + quad) ^ l16)) * 8]);
#pragma unroll
    for (int mt = 0; mt < 2; mt++) {
      int o = oh * 128 + w * 32 + mt * 16 + l16;
      f16x8 ah = *(const f16x8*)(w2h + o * C2_ + ks * 32 + quad * 8);
#pragma unroll
      for (int nt = 0; nt < 4; nt++)
        acc[mt][nt] = __builtin_amdgcn_mfma_f32_16x16x32_f16(ah, bfr[nt], acc[mt][nt], 0, 0, 0);
    }
  }
#pragma unroll
  for (int mt = 0; mt < 2; mt++)
#pragma unroll
    for (int rg = 0; rg < 4; rg++) {
      int o = oh * 128 + w * 32 + mt * 16 + quad * 4 + rg;
      float so = scale[o], bo = b2[o];
#pragma unroll
      for (int nt = 0; nt < 4; nt++) {
        int p = pt * 64 + nt * 16 + l16;
        long xo = ((long)b * C_ + o) * N_ + p;
        out[xo] = (acc[mt][nt][rg] + bo) * so + x[xo];
      }
    }
}

extern "C" void kernel_launch(void* const* d_in, const int* in_sizes, int n_in,
                              void* d_out, int out_size, void* d_ws, size_t ws_size,
                              hipStream_t stream) {
  const float* x     = (const float*)d_in[0];
  const float* W1    = (const float*)d_in[1];
  const float* b1    = (const float*)d_in[2];
  const float* W2    = (const float*)d_in[3];
  const float* b2    = (const float*)d_in[4];
  const float* scale = (const float*)d_in[5];
  float* outp = (float*)d_out;

  const size_t NE = (size_t)B_ * N_ * C2_;       // 4,194,304
  const int ns = 2;   // residency is VGPR-capped at 2 WG/CU; ns>2 only adds Op traffic (R5)

  f16* Y   = (f16*)d_ws;                         // 8 MiB
  f16* Yt  = Y + NE;                             // 8 MiB
  f16* Op  = Yt + NE;                            // ns x 8 MiB (unnormalized)
  float* ls = (float*)(Op + (size_t)ns * NE);    // ns x 32768 f32 row sums
  f16* w1h = (f16*)(ls + (size_t)ns * 32768);
  f16* w2h = w1h + 32768;

  prep_kernel <<<dim3(128),       dim3(256), 0, stream>>>(W1, W2, w1h, w2h);
  conv1_kernel<<<dim3(8, 128),    dim3(256), 0, stream>>>(x, w1h, b1, Y, Yt);
  attn_kernel <<<dim3(8, 32, ns), dim3(256), 0, stream>>>(Y, Yt, Op, ls);
  conv2_kernel<<<dim3(8, 64, 2),  dim3(256), 0, stream>>>(Op, ls, w2h, b2, scale, x, outp, ns);
}

// Round 10
// 208.646 us; speedup vs baseline: 1.0068x; 1.0068x over previous
//
#include <hip/hip_runtime.h>

#define B_  8
#define C_  256
#define C2_ 128
#define N_  4096
#define LOG2E 1.44269504088896f

typedef _Float16 f16;
typedef _Float16 f16x4 __attribute__((ext_vector_type(4)));
typedef _Float16 f16x8 __attribute__((ext_vector_type(8)));
typedef float f32x4  __attribute__((ext_vector_type(4)));

static __device__ __forceinline__ unsigned pk2(float a, float b) {
  return __builtin_bit_cast(unsigned, __builtin_amdgcn_cvt_pkrtz(a, b));  // v_cvt_pkrtz_f16_f32
}

// quad-row swap: r0 = {a.q0, b.q0, a.q2, b.q2}, r1 = {a.q1, b.q1, a.q3, b.q3}
static __device__ __forceinline__ void plane16_swap(unsigned a, unsigned b,
                                                    unsigned& r0, unsigned& r1) {
#if __has_builtin(__builtin_amdgcn_permlane16_swap)
  auto r = __builtin_amdgcn_permlane16_swap(a, b, false, false);
  r0 = (unsigned)r[0]; r1 = (unsigned)r[1];
#else
  asm volatile("v_permlane16_swap_b32 %0, %1" : "+v"(a), "+v"(b));
  r0 = a; r1 = b;
#endif
}

// direct global->LDS 16B copy: per-lane global src, wave-uniform LDS base + lane*16
static __device__ __forceinline__ void gload16(const void* g, void* l) {
  __builtin_amdgcn_global_load_lds(
      (const __attribute__((address_space(1))) unsigned int*)g,
      (__attribute__((address_space(3))) unsigned int*)l, 16, 0, 0);
}

// ---------------------------------------------------------------------------
// prep: cast W1/W2 to f16 once (32768 elements each)
// ---------------------------------------------------------------------------
__global__ __launch_bounds__(256)
void prep_kernel(const float* __restrict__ W1, const float* __restrict__ W2,
                 f16* __restrict__ w1h, f16* __restrict__ w2h)
{
  int i = blockIdx.x * 256 + threadIdx.x;   // grid 128 -> 32768
  w1h[i] = (f16)W1[i];
  w2h[i] = (f16)W2[i];
}

// ---------------------------------------------------------------------------
// conv1 v2: identical math to baseline, but x is cast to f16 AT STAGING
// (plain round-to-nearest casts -> Ah contents bit-identical to the old
// "(f16) at transpose" path). LDS 48 KB -> 32 KB: if conv1 was LDS-capped
// at 3 blocks/CU this unlocks 4-5.
// ---------------------------------------------------------------------------
__global__ __launch_bounds__(256, 3)
void conv1_kernel(const float* __restrict__ x,
                  const f16* __restrict__ w1h,
                  const float* __restrict__ b1,
                  f16* __restrict__ Y, f16* __restrict__ Yt)
{
  __shared__ __align__(16) char smem[32768];
  f16* Xh = (f16*)smem;                // [256 c][32 n] f16, 4-f16-block XOR (16 KB)
  f16* Ah = (f16*)(smem + 16384);      // [32 n][256 k] f16 XOR-8 (16 KB)
  f16* T  = (f16*)smem;                // [128 c2][40 n] epilogue alias

  const int t = threadIdx.x;
  const int w = t >> 6, lane = t & 63, quad = lane >> 4, l16 = lane & 15;
  const int b = blockIdx.x, nt0 = blockIdx.y;

  // stage all 256c x 32n, cvt f32->f16 (RNE casts, same values as baseline)
#pragma unroll
  for (int pass = 0; pass < 8; pass++) {
    int c  = (t >> 3) + pass * 32;            // 0..255
    int n4 = t & 7;
    float4 v = *(const float4*)(x + ((long)(b * C_ + c)) * N_ + nt0 * 32 + n4 * 4);
    f16x4 h = {(f16)v.x, (f16)v.y, (f16)v.z, (f16)v.w};
    *(f16x4*)(&Xh[c * 32 + (n4 ^ (c & 7)) * 4]) = h;
  }
  __syncthreads();
  // transpose into Ah [n][k] XOR-8 (pure f16 copies)
#pragma unroll
  for (int pass = 0; pass < 4; pass++) {
    int n  = t & 31;
    int kb = (t >> 5) + pass * 8;             // 0..31
    f16x8 vh;
#pragma unroll
    for (int jj = 0; jj < 8; jj++) {
      int cc = kb * 8 + jj;
      vh[jj] = Xh[cc * 32 + ((n >> 2) ^ (cc & 7)) * 4 + (n & 3)];
    }
    *(f16x8*)(&Ah[n * 256 + (kb ^ (n & 7)) * 8]) = vh;
  }
  __syncthreads();

  // B-frags from global (L2-hot, shared by all WGs)
  f16x8 bh[2][8];
#pragma unroll
  for (int nt = 0; nt < 2; nt++) {
    int c2 = w * 32 + nt * 16 + l16;
#pragma unroll
    for (int ks = 0; ks < 8; ks++)
      bh[nt][ks] = *(const f16x8*)(w1h + c2 * C_ + ks * 32 + quad * 8);
  }

  f32x4 acc[2][2];
#pragma unroll
  for (int i = 0; i < 2; i++)
#pragma unroll
    for (int j = 0; j < 2; j++) acc[i][j] = (f32x4){0.f, 0.f, 0.f, 0.f};

#pragma unroll
  for (int ks = 0; ks < 8; ks++)
#pragma unroll
    for (int mt = 0; mt < 2; mt++) {
      f16x8 ah = *(const f16x8*)(&Ah[(mt * 16 + l16) * 256 + (((ks * 4 + quad) ^ (l16 & 7))) * 8]);
#pragma unroll
      for (int nt = 0; nt < 2; nt++)
        acc[mt][nt] = __builtin_amdgcn_mfma_f32_16x16x32_f16(ah, bh[nt][ks], acc[mt][nt], 0, 0, 0);
    }
  __syncthreads();   // Xh dead -> T alias safe

  // epilogue -> T[c2][n]
#pragma unroll
  for (int nt = 0; nt < 2; nt++) {
    int c2 = w * 32 + nt * 16 + l16;
    float bv = b1[c2];
#pragma unroll
    for (int mt = 0; mt < 2; mt++)
#pragma unroll
      for (int rg = 0; rg < 4; rg++) {
        int n = mt * 16 + quad * 4 + rg;
        T[c2 * 40 + n] = (f16)(acc[mt][nt][rg] + bv);
      }
  }
  __syncthreads();
  // Yt[c2][n]: vec8 along n
#pragma unroll
  for (int pass = 0; pass < 2; pass++) {
    int r  = (t >> 2) + pass * 64;            // c2 0..127
    int c8 = (t & 3) * 8;                     // n
    f16x8 v = *(const f16x8*)(&T[r * 40 + c8]);
    *(f16x8*)(Yt + ((long)(b * C2_ + r)) * N_ + nt0 * 32 + c8) = v;
  }
  // Y[n][c2]: gather
#pragma unroll
  for (int pass = 0; pass < 2; pass++) {
    int row = t & 31;
    int cg  = (t >> 5) + pass * 8;            // c2-block 0..15
    f16x8 v;
#pragma unroll
    for (int jj = 0; jj < 8; jj++) v[jj] = T[(cg * 8 + jj) * 40 + row];
    *(f16x8*)(Y + ((long)(b * N_ + nt0 * 32 + row)) * C2_ + cg * 8) = v;
  }
}

// ---------------------------------------------------------------------------
// attn v9 (UNCHANGED from R9 — best measured: ~100 us, 96 arch VGPR):
// swapped QK^T, register P via permlane32+permlane16, conflict-free
// 16x16x32 PV, double-buffered direct global->LDS staging.
// launch_bounds(256,2): do NOT tighten (R4: forced 64 VGPR = 717 MB spill).
// ---------------------------------------------------------------------------
__global__ __launch_bounds__(256, 2)
void attn_kernel(const f16* __restrict__ Y, const f16* __restrict__ Yt,
                 f16* __restrict__ Op, float* __restrict__ ls)
{
  __shared__ f16 Ks[2][64 * 128];   // [key][d]  16B-block pos = (d>>3) ^ (key&15)
  __shared__ f16 Vs[2][128 * 64];   // [d][k]    pos = (k>>3) ^ (d&7)
  __shared__ float nsqf[128];

  const int t = threadIdx.x;
  const int w = t >> 6, lane = t & 63, quad = lane >> 4, l16 = lane & 15;
  const int b = blockIdx.x, qt = blockIdx.y, s = blockIdx.z;
  const int ns = gridDim.z;
  const f16* Yb  = Y  + (long)b * N_ * C2_;
  const f16* Ytb = Yt + (long)b * C2_ * N_;
  const int g0 = (s * 64) / ns;        // first 64-key tile of this split
  const int g1 = ((s + 1) * 64) / ns;  // one past last

  int koff[4], voff[4];
#pragma unroll
  for (int i = 0; i < 4; i++) {
    int p = w + 4 * i;
    int r = 4 * p + (lane >> 4);
    koff[i] = r * C2_ + ((l16 ^ (r & 15)) * 8);
    int d = 8 * p + (lane >> 3);
    voff[i] = d * N_ + (((lane & 7) ^ (d & 7)) * 8);
  }

  // Q frags (A/B-frag layout identical for 16x16x32): row q=l16, d-chunk quad*8
  f16x8 qf[2][4];
#pragma unroll
  for (int mt = 0; mt < 2; mt++)
#pragma unroll
    for (int ks = 0; ks < 4; ks++)
      qf[mt][ks] = *(const f16x8*)(Yb + (long)(qt * 128 + w * 32 + mt * 16 + l16) * C2_ + ks * 32 + quad * 8);

  // per-row |y_q|^2 (exact same f16 values the MFMA sees)
  {
    int r = t >> 1, half = t & 1;
    float ss = 0.f;
#pragma unroll
    for (int j = 0; j < 8; j++) {
      f16x8 v = *(const f16x8*)(Yb + (long)(qt * 128 + r) * C2_ + half * 64 + j * 8);
#pragma unroll
      for (int e = 0; e < 8; e++) { float f = (float)v[e]; ss = fmaf(f, f, ss); }
    }
    ss += __shfl_xor(ss, 1);
    if (!half) nsqf[r] = ss;
  }

  // prologue: stage first tile of this split into buffer 0 (direct to LDS)
  {
    const int kb0 = g0 * 64;
    const f16* gk = Yb + (long)kb0 * C2_;
    const f16* gv = Ytb + kb0;
#pragma unroll
    for (int i = 0; i < 4; i++) {
      gload16(gk + koff[i], &Ks[0][(w + 4 * i) * 512]);
      gload16(gv + voff[i], &Vs[0][(w + 4 * i) * 512]);
    }
  }
  __syncthreads();   // drains vmcnt (gload) + lgkm (nsqf write)

  // fixed per-row max (log2 units), per-lane by q=l16
  float nm[2];
  nm[0] = nsqf[w * 32 + l16] * LOG2E;
  nm[1] = nsqf[w * 32 + 16 + l16] * LOG2E;

  f16x8 ones8;
#pragma unroll
  for (int j = 0; j < 8; j++) ones8[j] = (f16)1.0f;

  f32x4 Oa[2][8];                 // C-layout: row q = quad*4+rg, col d = l16
#pragma unroll
  for (int i = 0; i < 2; i++)
#pragma unroll
    for (int j = 0; j < 8; j++) Oa[i][j] = (f32x4){0.f, 0.f, 0.f, 0.f};
  f32x4 lac[2] = {(f32x4){0.f,0.f,0.f,0.f}, (f32x4){0.f,0.f,0.f,0.f}};

  int cur = 0;
#pragma unroll 1
  for (int g = g0; g < g1; g++) {
    if (g + 1 < g1) {
      int nb = (g + 1) * 64;
      const f16* gk = Yb + (long)nb * C2_;
      const f16* gv = Ytb + nb;
#pragma unroll
      for (int i = 0; i < 4; i++) {
        gload16(gk + koff[i], &Ks[cur ^ 1][(w + 4 * i) * 512]);
        gload16(gv + voff[i], &Vs[cur ^ 1][(w + 4 * i) * 512]);
      }
    }

    // ---- QKT half A: S[0],S[1] (nt=0,1) complete first ----
    f32x4 S[4][2];
#pragma unroll
    for (int i = 0; i < 4; i++)
#pragma unroll
      for (int j = 0; j < 2; j++) S[i][j] = (f32x4){0.f, 0.f, 0.f, 0.f};
#pragma unroll
    for (int ks = 0; ks < 4; ks++) {
      f16x8 b0 = *(const f16x8*)(&Ks[cur][(0 * 16 + l16) * 128 + (((ks * 4 + quad) ^ l16)) * 8]);
      f16x8 b1 = *(const f16x8*)(&Ks[cur][(1 * 16 + l16) * 128 + (((ks * 4 + quad) ^ l16)) * 8]);
      __builtin_amdgcn_s_setprio(1);
#pragma unroll
      for (int mt = 0; mt < 2; mt++) {
        S[0][mt] = __builtin_amdgcn_mfma_f32_16x16x32_f16(b0, qf[mt][ks], S[0][mt], 0, 0, 0);
        S[1][mt] = __builtin_amdgcn_mfma_f32_16x16x32_f16(b1, qf[mt][ks], S[1][mt], 0, 0, 0);
      }
      __builtin_amdgcn_s_setprio(0);
    }
    // ---- QKT half B ----
#pragma unroll
    for (int ks = 0; ks < 4; ks++) {
      f16x8 b2 = *(const f16x8*)(&Ks[cur][(2 * 16 + l16) * 128 + (((ks * 4 + quad) ^ l16)) * 8]);
      f16x8 b3 = *(const f16x8*)(&Ks[cur][(3 * 16 + l16) * 128 + (((ks * 4 + quad) ^ l16)) * 8]);
      __builtin_amdgcn_s_setprio(1);
#pragma unroll
      for (int mt = 0; mt < 2; mt++) {
        S[2][mt] = __builtin_amdgcn_mfma_f32_16x16x32_f16(b2, qf[mt][ks], S[2][mt], 0, 0, 0);
        S[3][mt] = __builtin_amdgcn_mfma_f32_16x16x32_f16(b3, qf[mt][ks], S[3][mt], 0, 0, 0);
      }
      __builtin_amdgcn_s_setprio(0);
    }

    // ---- exp + exchange half0 (S[0],S[1] -> pa0) ----
    f16x8 pa0[2];
#pragma unroll
    for (int mt = 0; mt < 2; mt++) {
      float n0 = nm[mt];
      unsigned xa0 = pk2(exp2f(fminf(fmaf(S[0][mt][0], LOG2E, -n0), 11.0f)),
                         exp2f(fminf(fmaf(S[0][mt][1], LOG2E, -n0), 11.0f)));
      unsigned xa1 = pk2(exp2f(fminf(fmaf(S[0][mt][2], LOG2E, -n0), 11.0f)),
                         exp2f(fminf(fmaf(S[0][mt][3], LOG2E, -n0), 11.0f)));
      unsigned xb0 = pk2(exp2f(fminf(fmaf(S[1][mt][0], LOG2E, -n0), 11.0f)),
                         exp2f(fminf(fmaf(S[1][mt][1], LOG2E, -n0), 11.0f)));
      unsigned xb1 = pk2(exp2f(fminf(fmaf(S[1][mt][2], LOG2E, -n0), 11.0f)),
                         exp2f(fminf(fmaf(S[1][mt][3], LOG2E, -n0), 11.0f)));
      union { unsigned u[4]; f16x8 v; } P;
      {
        auto c = __builtin_amdgcn_permlane32_swap(xa0, xb0, false, false);
        plane16_swap((unsigned)c[0], (unsigned)c[1], P.u[0], P.u[2]);
      }
      {
        auto c = __builtin_amdgcn_permlane32_swap(xa1, xb1, false, false);
        plane16_swap((unsigned)c[0], (unsigned)c[1], P.u[1], P.u[3]);
      }
      pa0[mt] = P.v;
    }

    // ---- PV0 (ks2=0) ----
    {
      f16x8 vb[8];
#pragma unroll
      for (int dt = 0; dt < 8; dt++)
        vb[dt] = *(const f16x8*)(&Vs[cur][(dt * 16 + l16) * 64 + (((0 * 4 + quad) ^ (l16 & 7))) * 8]);
      __builtin_amdgcn_s_setprio(1);
#pragma unroll
      for (int mt = 0; mt < 2; mt++) {
#pragma unroll
        for (int dt = 0; dt < 8; dt++)
          Oa[mt][dt] = __builtin_amdgcn_mfma_f32_16x16x32_f16(pa0[mt], vb[dt], Oa[mt][dt], 0, 0, 0);
        lac[mt] = __builtin_amdgcn_mfma_f32_16x16x32_f16(pa0[mt], ones8, lac[mt], 0, 0, 0);
      }
      __builtin_amdgcn_s_setprio(0);
    }

    // ---- exp + exchange half1 (S[2],S[3] -> pa1) ----
    f16x8 pa1[2];
#pragma unroll
    for (int mt = 0; mt < 2; mt++) {
      float n0 = nm[mt];
      unsigned xa0 = pk2(exp2f(fminf(fmaf(S[2][mt][0], LOG2E, -n0), 11.0f)),
                         exp2f(fminf(fmaf(S[2][mt][1], LOG2E, -n0), 11.0f)));
      unsigned xa1 = pk2(exp2f(fminf(fmaf(S[2][mt][2], LOG2E, -n0), 11.0f)),
                         exp2f(fminf(fmaf(S[2][mt][3], LOG2E, -n0), 11.0f)));
      unsigned xb0 = pk2(exp2f(fminf(fmaf(S[3][mt][0], LOG2E, -n0), 11.0f)),
                         exp2f(fminf(fmaf(S[3][mt][1], LOG2E, -n0), 11.0f)));
      unsigned xb1 = pk2(exp2f(fminf(fmaf(S[3][mt][2], LOG2E, -n0), 11.0f)),
                         exp2f(fminf(fmaf(S[3][mt][3], LOG2E, -n0), 11.0f)));
      union { unsigned u[4]; f16x8 v; } P;
      {
        auto c = __builtin_amdgcn_permlane32_swap(xa0, xb0, false, false);
        plane16_swap((unsigned)c[0], (unsigned)c[1], P.u[0], P.u[2]);
      }
      {
        auto c = __builtin_amdgcn_permlane32_swap(xa1, xb1, false, false);
        plane16_swap((unsigned)c[0], (unsigned)c[1], P.u[1], P.u[3]);
      }
      pa1[mt] = P.v;
    }

    // ---- PV1 (ks2=1) ----
    {
      f16x8 vb[8];
#pragma unroll
      for (int dt = 0; dt < 8; dt++)
        vb[dt] = *(const f16x8*)(&Vs[cur][(dt * 16 + l16) * 64 + (((1 * 4 + quad) ^ (l16 & 7))) * 8]);
      __builtin_amdgcn_s_setprio(1);
#pragma unroll
      for (int mt = 0; mt < 2; mt++) {
#pragma unroll
        for (int dt = 0; dt < 8; dt++)
          Oa[mt][dt] = __builtin_amdgcn_mfma_f32_16x16x32_f16(pa1[mt], vb[dt], Oa[mt][dt], 0, 0, 0);
        lac[mt] = __builtin_amdgcn_mfma_f32_16x16x32_f16(pa1[mt], ones8, lac[mt], 0, 0, 0);
      }
      __builtin_amdgcn_s_setprio(0);
    }

    __syncthreads();   // all buf[cur] reads done + prefetch gloads drained
    cur ^= 1;
  }

  // epilogue: unnormalized O + row sums l (C-layout: row q, col d)
  const long rbase = ((long)s * B_ + b) * N_ + qt * 128;
#pragma unroll
  for (int mt = 0; mt < 2; mt++)
#pragma unroll
    for (int rg = 0; rg < 4; rg++) {
      int r = w * 32 + mt * 16 + quad * 4 + rg;
#pragma unroll
      for (int dt = 0; dt < 8; dt++)
        Op[(rbase + r) * C2_ + dt * 16 + l16] = (f16)Oa[mt][dt][rg];
      if (l16 == 0) ls[rbase + r] = lac[mt][rg];
    }
}

// ---------------------------------------------------------------------------
// conv2 v2: staging/transpose/MFMA unchanged; epilogue now routes acc through
// a padded LDS bounce (Or/Bsw dead by then) so the x-residual loads and out
// stores are float4 / 256B-segment coalesced (was 64B-segment scalar f32).
// Arithmetic identical: out = (acc + b2)*scale + x, same order. Obuf pad=68
// keeps rows 16B-aligned and bank-spread. Grid (8, 64, 2).
// ---------------------------------------------------------------------------
__global__ __launch_bounds__(256, 4)
void conv2_kernel(const f16* __restrict__ Op, const float* __restrict__ ls,
                  const f16* __restrict__ w2h,
                  const float* __restrict__ b2,
                  const float* __restrict__ scale,
                  const float* __restrict__ x,
                  float* __restrict__ out, int ns)
{
  __shared__ __align__(16) char smem2[35328];
  f16*   Or   = (f16*)smem2;                    // [128][72]        (18432 B)
  f16*   Bsw  = (f16*)(smem2 + 18432);          // [64][128] XOR-16 (16384 B)
  float* invL = (float*)(smem2 + 34816);        // [128]            (512 B)
  float* Obuf = (float*)smem2;                  // [128][68] alias  (34816 B)

  const int t = threadIdx.x;
  const int w = t >> 6, lane = t & 63, quad = lane >> 4, l16 = lane & 15;
  const int b = blockIdx.x, pt = blockIdx.y, oh = blockIdx.z;
  const long base0 = (long)b * 524288;            // batch offset within a split

  if (t < 128) {
    int q = t * 32 + (pt >> 1);
    float l = 0.f;
    for (int si = 0; si < ns; si++)
      l += ls[(long)si * 32768 + (long)b * N_ + q];
    invL[t] = 1.0f / fmaxf(l, 1e-20f);
  }
  __syncthreads();

#pragma unroll
  for (int pass = 0; pass < 4; pass++) {
    int j = (t >> 3) + pass * 32;            // 0..127
    int c8 = (t & 7) * 8;                    // p_local
    float fa[8] = {0.f,0.f,0.f,0.f,0.f,0.f,0.f,0.f};
    for (int si = 0; si < ns; si++) {
      f16x8 a = *(const f16x8*)(Op + (long)si * 4194304 + base0 + (long)j * N_ + pt * 64 + c8);
#pragma unroll
      for (int jj = 0; jj < 8; jj++) fa[jj] += (float)a[jj];
    }
    float iv = invL[j];
    f16x8 r;
#pragma unroll
    for (int jj = 0; jj < 8; jj++)
      r[jj] = (f16)(fa[jj] * iv);
    *(f16x8*)(&Or[j * 72 + c8]) = r;
  }
  __syncthreads();
#pragma unroll
  for (int pass = 0; pass < 4; pass++) {
    int p = t & 63;
    int q = (t >> 6) + pass * 4;             // j-block 0..15
    f16x8 vv;
#pragma unroll
    for (int jj = 0; jj < 8; jj++) vv[jj] = Or[(q * 8 + jj) * 72 + p];
    *(f16x8*)(&Bsw[p * 128 + ((q ^ (p & 15))) * 8]) = vv;
  }
  __syncthreads();

  f32x4 acc[2][4];
#pragma unroll
  for (int i = 0; i < 2; i++)
#pragma unroll
    for (int j = 0; j < 4; j++) acc[i][j] = (f32x4){0.f, 0.f, 0.f, 0.f};

#pragma unroll
  for (int ks = 0; ks < 4; ks++) {
    f16x8 bfr[4];
#pragma unroll
    for (int nt = 0; nt < 4; nt++)
      bfr[nt] = *(const f16x8*)(&Bsw[(nt * 16 + l16) * 128 + (((ks * 4 + quad) ^ l16)) * 8]);
#pragma unroll
    for (int mt = 0; mt < 2; mt++) {
      int o = oh * 128 + w * 32 + mt * 16 + l16;
      f16x8 ah = *(const f16x8*)(w2h + o * C2_ + ks * 32 + quad * 8);
#pragma unroll
      for (int nt = 0; nt < 4; nt++)
        acc[mt][nt] = __builtin_amdgcn_mfma_f32_16x16x32_f16(ah, bfr[nt], acc[mt][nt], 0, 0, 0);
    }
  }

  // ---- coalesced epilogue: acc -> Obuf -> float4 out/x ----
  __syncthreads();   // all Bsw reads done; Obuf alias safe
#pragma unroll
  for (int mt = 0; mt < 2; mt++)
#pragma unroll
    for (int nt = 0; nt < 4; nt++)
#pragma unroll
      for (int rg = 0; rg < 4; rg++)
        Obuf[(w * 32 + mt * 16 + quad * 4 + rg) * 68 + nt * 16 + l16] = acc[mt][nt][rg];
  __syncthreads();
#pragma unroll
  for (int pass = 0; pass < 8; pass++) {
    int idx = pass * 256 + t;          // 0..2047 float4 slots
    int ol  = idx >> 4;                // 0..127
    int p4  = (idx & 15) * 4;          // 0..60
    float4 v = *(const float4*)(&Obuf[ol * 68 + p4]);
    int o = oh * 128 + ol;
    float so = scale[o], bo = b2[o];
    long xo = ((long)b * C_ + o) * N_ + pt * 64 + p4;
    float4 xv = *(const float4*)(x + xo);
    float4 r;
    r.x = (v.x + bo) * so + xv.x;
    r.y = (v.y + bo) * so + xv.y;
    r.z = (v.z + bo) * so + xv.z;
    r.w = (v.w + bo) * so + xv.w;
    *(float4*)(out + xo) = r;
  }
}

extern "C" void kernel_launch(void* const* d_in, const int* in_sizes, int n_in,
                              void* d_out, int out_size, void* d_ws, size_t ws_size,
                              hipStream_t stream) {
  const float* x     = (const float*)d_in[0];
  const float* W1    = (const float*)d_in[1];
  const float* b1    = (const float*)d_in[2];
  const float* W2    = (const float*)d_in[3];
  const float* b2    = (const float*)d_in[4];
  const float* scale = (const float*)d_in[5];
  float* outp = (float*)d_out;

  const size_t NE = (size_t)B_ * N_ * C2_;       // 4,194,304
  const int ns = 2;   // residency is VGPR-capped at 2 WG/CU; ns>2 only adds Op traffic (R5)

  f16* Y   = (f16*)d_ws;                         // 8 MiB
  f16* Yt  = Y + NE;                             // 8 MiB
  f16* Op  = Yt + NE;                            // ns x 8 MiB (unnormalized)
  float* ls = (float*)(Op + (size_t)ns * NE);    // ns x 32768 f32 row sums
  f16* w1h = (f16*)(ls + (size_t)ns * 32768);
  f16* w2h = w1h + 32768;

  prep_kernel <<<dim3(128),       dim3(256), 0, stream>>>(W1, W2, w1h, w2h);
  conv1_kernel<<<dim3(8, 128),    dim3(256), 0, stream>>>(x, w1h, b1, Y, Yt);
  attn_kernel <<<dim3(8, 32, ns), dim3(256), 0, stream>>>(Y, Yt, Op, ls);
  conv2_kernel<<<dim3(8, 64, 2),  dim3(256), 0, stream>>>(Op, ls, w2h, b2, scale, x, outp, ns);
}

// Round 11
// 197.813 us; speedup vs baseline: 1.0619x; 1.0548x over previous
//
#include <hip/hip_runtime.h>

#define B_  8
#define C_  256
#define C2_ 128
#define N_  4096
#define LOG2E 1.44269504088896f

typedef _Float16 f16;
typedef _Float16 f16x4 __attribute__((ext_vector_type(4)));
typedef _Float16 f16x8 __attribute__((ext_vector_type(8)));
typedef float f32x4  __attribute__((ext_vector_type(4)));

static __device__ __forceinline__ unsigned pk2(float a, float b) {
  return __builtin_bit_cast(unsigned, __builtin_amdgcn_cvt_pkrtz(a, b));  // v_cvt_pkrtz_f16_f32
}

// quad-row swap: r0 = {a.q0, b.q0, a.q2, b.q2}, r1 = {a.q1, b.q1, a.q3, b.q3}
static __device__ __forceinline__ void plane16_swap(unsigned a, unsigned b,
                                                    unsigned& r0, unsigned& r1) {
#if __has_builtin(__builtin_amdgcn_permlane16_swap)
  auto r = __builtin_amdgcn_permlane16_swap(a, b, false, false);
  r0 = (unsigned)r[0]; r1 = (unsigned)r[1];
#else
  asm volatile("v_permlane16_swap_b32 %0, %1" : "+v"(a), "+v"(b));
  r0 = a; r1 = b;
#endif
}

// direct global->LDS 16B copy: per-lane global src, wave-uniform LDS base + lane*16
static __device__ __forceinline__ void gload16(const void* g, void* l) {
  __builtin_amdgcn_global_load_lds(
      (const __attribute__((address_space(1))) unsigned int*)g,
      (__attribute__((address_space(3))) unsigned int*)l, 16, 0, 0);
}

// ---------------------------------------------------------------------------
// prep: cast W1/W2 to f16 once (32768 elements each)
// ---------------------------------------------------------------------------
__global__ __launch_bounds__(256)
void prep_kernel(const float* __restrict__ W1, const float* __restrict__ W2,
                 f16* __restrict__ w1h, f16* __restrict__ w2h)
{
  int i = blockIdx.x * 256 + threadIdx.x;   // grid 128 -> 32768
  w1h[i] = (f16)W1[i];
  w2h[i] = (f16)W2[i];
}

// ---------------------------------------------------------------------------
// conv1 (R10-verified): x cast to f16 at staging (RNE, bit-identical to
// baseline values), LDS 32 KB.
// ---------------------------------------------------------------------------
__global__ __launch_bounds__(256, 3)
void conv1_kernel(const float* __restrict__ x,
                  const f16* __restrict__ w1h,
                  const float* __restrict__ b1,
                  f16* __restrict__ Y, f16* __restrict__ Yt)
{
  __shared__ __align__(16) char smem[32768];
  f16* Xh = (f16*)smem;                // [256 c][32 n] f16, 4-f16-block XOR (16 KB)
  f16* Ah = (f16*)(smem + 16384);      // [32 n][256 k] f16 XOR-8 (16 KB)
  f16* T  = (f16*)smem;                // [128 c2][40 n] epilogue alias

  const int t = threadIdx.x;
  const int w = t >> 6, lane = t & 63, quad = lane >> 4, l16 = lane & 15;
  const int b = blockIdx.x, nt0 = blockIdx.y;

#pragma unroll
  for (int pass = 0; pass < 8; pass++) {
    int c  = (t >> 3) + pass * 32;            // 0..255
    int n4 = t & 7;
    float4 v = *(const float4*)(x + ((long)(b * C_ + c)) * N_ + nt0 * 32 + n4 * 4);
    f16x4 h = {(f16)v.x, (f16)v.y, (f16)v.z, (f16)v.w};
    *(f16x4*)(&Xh[c * 32 + (n4 ^ (c & 7)) * 4]) = h;
  }
  __syncthreads();
#pragma unroll
  for (int pass = 0; pass < 4; pass++) {
    int n  = t & 31;
    int kb = (t >> 5) + pass * 8;             // 0..31
    f16x8 vh;
#pragma unroll
    for (int jj = 0; jj < 8; jj++) {
      int cc = kb * 8 + jj;
      vh[jj] = Xh[cc * 32 + ((n >> 2) ^ (cc & 7)) * 4 + (n & 3)];
    }
    *(f16x8*)(&Ah[n * 256 + (kb ^ (n & 7)) * 8]) = vh;
  }
  __syncthreads();

  f16x8 bh[2][8];
#pragma unroll
  for (int nt = 0; nt < 2; nt++) {
    int c2 = w * 32 + nt * 16 + l16;
#pragma unroll
    for (int ks = 0; ks < 8; ks++)
      bh[nt][ks] = *(const f16x8*)(w1h + c2 * C_ + ks * 32 + quad * 8);
  }

  f32x4 acc[2][2];
#pragma unroll
  for (int i = 0; i < 2; i++)
#pragma unroll
    for (int j = 0; j < 2; j++) acc[i][j] = (f32x4){0.f, 0.f, 0.f, 0.f};

#pragma unroll
  for (int ks = 0; ks < 8; ks++)
#pragma unroll
    for (int mt = 0; mt < 2; mt++) {
      f16x8 ah = *(const f16x8*)(&Ah[(mt * 16 + l16) * 256 + (((ks * 4 + quad) ^ (l16 & 7))) * 8]);
#pragma unroll
      for (int nt = 0; nt < 2; nt++)
        acc[mt][nt] = __builtin_amdgcn_mfma_f32_16x16x32_f16(ah, bh[nt][ks], acc[mt][nt], 0, 0, 0);
    }
  __syncthreads();   // Xh dead -> T alias safe

#pragma unroll
  for (int nt = 0; nt < 2; nt++) {
    int c2 = w * 32 + nt * 16 + l16;
    float bv = b1[c2];
#pragma unroll
    for (int mt = 0; mt < 2; mt++)
#pragma unroll
      for (int rg = 0; rg < 4; rg++) {
        int n = mt * 16 + quad * 4 + rg;
        T[c2 * 40 + n] = (f16)(acc[mt][nt][rg] + bv);
      }
  }
  __syncthreads();
#pragma unroll
  for (int pass = 0; pass < 2; pass++) {
    int r  = (t >> 2) + pass * 64;            // c2 0..127
    int c8 = (t & 3) * 8;                     // n
    f16x8 v = *(const f16x8*)(&T[r * 40 + c8]);
    *(f16x8*)(Yt + ((long)(b * C2_ + r)) * N_ + nt0 * 32 + c8) = v;
  }
#pragma unroll
  for (int pass = 0; pass < 2; pass++) {
    int row = t & 31;
    int cg  = (t >> 5) + pass * 8;            // c2-block 0..15
    f16x8 v;
#pragma unroll
    for (int jj = 0; jj < 8; jj++) v[jj] = T[(cg * 8 + jj) * 40 + row];
    *(f16x8*)(Y + ((long)(b * N_ + nt0 * 32 + row)) * C2_ + cg * 8) = v;
  }
}

// ---------------------------------------------------------------------------
// attn v10: CROSS-TILE SOFTWARE PIPELINE. Iter i (tile g) computes QK^T(g)
// and PV(g-1) — two INDEPENDENT MFMA streams — with exp/exchange(g) filling
// under PV(g-1). P carried across the barrier in registers (pa_prev, 16 VGPR).
// Buffers phase-shifted: iter i issues gloads K(g+1)->Ks[i&1^1], V(g)->Vs[i&1];
// both land by barrier(i); K(g+1) read iter i+1 (QKT), V(g) read iter i+1 (PV).
// Overwrite safety: every buffer reuse is separated by an intervening barrier
// (K[i&1^1] last read in QKT(g-1) before barrier(i-1); V[i&1] last read in
// PV(g-2) before barrier(i-1)). Tile accumulation order unchanged -> exact.
// launch_bounds(256,2): do NOT tighten (R4: forced 64 VGPR = 717 MB spill).
// ---------------------------------------------------------------------------
__global__ __launch_bounds__(256, 2)
void attn_kernel(const f16* __restrict__ Y, const f16* __restrict__ Yt,
                 f16* __restrict__ Op, float* __restrict__ ls)
{
  __shared__ f16 Ks[2][64 * 128];   // [key][d]  16B-block pos = (d>>3) ^ (key&15)
  __shared__ f16 Vs[2][128 * 64];   // [d][k]    pos = (k>>3) ^ (d&7)
  __shared__ float nsqf[128];

  const int t = threadIdx.x;
  const int w = t >> 6, lane = t & 63, quad = lane >> 4, l16 = lane & 15;
  const int b = blockIdx.x, qt = blockIdx.y, s = blockIdx.z;
  const int ns = gridDim.z;
  const f16* Yb  = Y  + (long)b * N_ * C2_;
  const f16* Ytb = Yt + (long)b * C2_ * N_;
  const int g0 = (s * 64) / ns;
  const int g1 = ((s + 1) * 64) / ns;
  const int nt_ = g1 - g0;

  int koff[4], voff[4];
#pragma unroll
  for (int i = 0; i < 4; i++) {
    int p = w + 4 * i;
    int r = 4 * p + (lane >> 4);
    koff[i] = r * C2_ + ((l16 ^ (r & 15)) * 8);
    int d = 8 * p + (lane >> 3);
    voff[i] = d * N_ + (((lane & 7) ^ (d & 7)) * 8);
  }

  // Q frags: row q=l16, d-chunk quad*8 (A/B layouts identical for 16x16x32)
  f16x8 qf[2][4];
#pragma unroll
  for (int mt = 0; mt < 2; mt++)
#pragma unroll
    for (int ks = 0; ks < 4; ks++)
      qf[mt][ks] = *(const f16x8*)(Yb + (long)(qt * 128 + w * 32 + mt * 16 + l16) * C2_ + ks * 32 + quad * 8);

  // per-row |y_q|^2 (same f16 values the MFMA sees)
  {
    int r = t >> 1, half = t & 1;
    float ss = 0.f;
#pragma unroll
    for (int j = 0; j < 8; j++) {
      f16x8 v = *(const f16x8*)(Yb + (long)(qt * 128 + r) * C2_ + half * 64 + j * 8);
#pragma unroll
      for (int e = 0; e < 8; e++) { float f = (float)v[e]; ss = fmaf(f, f, ss); }
    }
    ss += __shfl_xor(ss, 1);
    if (!half) nsqf[r] = ss;
  }

  // prologue: stage K(g0) into Ks[0] (V(g0) issued inside iter 0)
  {
    const f16* gk = Yb + (long)(g0 * 64) * C2_;
#pragma unroll
    for (int i = 0; i < 4; i++)
      gload16(gk + koff[i], &Ks[0][(w + 4 * i) * 512]);
  }
  __syncthreads();   // drains K(g0) vmcnt + nsqf lgkm

  float nm[2];
  nm[0] = nsqf[w * 32 + l16] * LOG2E;
  nm[1] = nsqf[w * 32 + 16 + l16] * LOG2E;

  f16x8 ones8;
#pragma unroll
  for (int j = 0; j < 8; j++) ones8[j] = (f16)1.0f;

  f32x4 Oa[2][8];                 // C-layout: row q = quad*4+rg, col d = l16
#pragma unroll
  for (int i = 0; i < 2; i++)
#pragma unroll
    for (int j = 0; j < 8; j++) Oa[i][j] = (f32x4){0.f, 0.f, 0.f, 0.f};
  f32x4 lac[2] = {(f32x4){0.f,0.f,0.f,0.f}, (f32x4){0.f,0.f,0.f,0.f}};

  f16x8 pa_prev[2][2];            // P(tile g-1), [ks2][mt] — loop-carried

#pragma unroll 1
  for (int i = 0; i < nt_; i++) {
    const int g = g0 + i;
    const int kb = i & 1;

    // issue gloads: K(g+1) -> Ks[kb^1], V(g) -> Vs[kb]; both land by barrier(i)
    if (i + 1 < nt_) {
      const f16* gk = Yb + (long)((g + 1) * 64) * C2_;
#pragma unroll
      for (int j = 0; j < 4; j++)
        gload16(gk + koff[j], &Ks[kb ^ 1][(w + 4 * j) * 512]);
    }
    {
      const f16* gv = Ytb + g * 64;
#pragma unroll
      for (int j = 0; j < 4; j++)
        gload16(gv + voff[j], &Vs[kb][(w + 4 * j) * 512]);
    }

    // ---- QK^T(g): S from Ks[kb] ----
    f32x4 S[4][2];
#pragma unroll
    for (int a = 0; a < 4; a++)
#pragma unroll
      for (int j = 0; j < 2; j++) S[a][j] = (f32x4){0.f, 0.f, 0.f, 0.f};
#pragma unroll
    for (int ks = 0; ks < 4; ks++) {
      f16x8 bfr[4];
#pragma unroll
      for (int nt = 0; nt < 4; nt++)
        bfr[nt] = *(const f16x8*)(&Ks[kb][(nt * 16 + l16) * 128 + (((ks * 4 + quad) ^ l16)) * 8]);
      __builtin_amdgcn_s_setprio(1);
#pragma unroll
      for (int nt = 0; nt < 4; nt++)
#pragma unroll
        for (int mt = 0; mt < 2; mt++)
          S[nt][mt] = __builtin_amdgcn_mfma_f32_16x16x32_f16(bfr[nt], qf[mt][ks], S[nt][mt], 0, 0, 0);
      __builtin_amdgcn_s_setprio(0);
    }

    // ---- PV(g-1): pa_prev x Vs[kb^1] — independent of QKT(g)/exp(g) ----
    if (i > 0) {
#pragma unroll
      for (int ks2 = 0; ks2 < 2; ks2++) {
        f16x8 vb[8];
#pragma unroll
        for (int dt = 0; dt < 8; dt++)
          vb[dt] = *(const f16x8*)(&Vs[kb ^ 1][(dt * 16 + l16) * 64 + (((ks2 * 4 + quad) ^ (l16 & 7))) * 8]);
        __builtin_amdgcn_s_setprio(1);
#pragma unroll
        for (int mt = 0; mt < 2; mt++) {
#pragma unroll
          for (int dt = 0; dt < 8; dt++)
            Oa[mt][dt] = __builtin_amdgcn_mfma_f32_16x16x32_f16(pa_prev[ks2][mt], vb[dt], Oa[mt][dt], 0, 0, 0);
          lac[mt] = __builtin_amdgcn_mfma_f32_16x16x32_f16(pa_prev[ks2][mt], ones8, lac[mt], 0, 0, 0);
        }
        __builtin_amdgcn_s_setprio(0);
      }
    }

    // ---- exp + exchange(g) -> pa_prev (fills under PV(g-1) MFMAs) ----
#pragma unroll
    for (int ks2 = 0; ks2 < 2; ks2++)
#pragma unroll
      for (int mt = 0; mt < 2; mt++) {
        float n0 = nm[mt];
        unsigned xa0 = pk2(exp2f(fminf(fmaf(S[2 * ks2][mt][0], LOG2E, -n0), 11.0f)),
                           exp2f(fminf(fmaf(S[2 * ks2][mt][1], LOG2E, -n0), 11.0f)));
        unsigned xa1 = pk2(exp2f(fminf(fmaf(S[2 * ks2][mt][2], LOG2E, -n0), 11.0f)),
                           exp2f(fminf(fmaf(S[2 * ks2][mt][3], LOG2E, -n0), 11.0f)));
        unsigned xb0 = pk2(exp2f(fminf(fmaf(S[2 * ks2 + 1][mt][0], LOG2E, -n0), 11.0f)),
                           exp2f(fminf(fmaf(S[2 * ks2 + 1][mt][1], LOG2E, -n0), 11.0f)));
        unsigned xb1 = pk2(exp2f(fminf(fmaf(S[2 * ks2 + 1][mt][2], LOG2E, -n0), 11.0f)),
                           exp2f(fminf(fmaf(S[2 * ks2 + 1][mt][3], LOG2E, -n0), 11.0f)));
        union { unsigned u[4]; f16x8 v; } P;
        {
          auto c = __builtin_amdgcn_permlane32_swap(xa0, xb0, false, false);
          plane16_swap((unsigned)c[0], (unsigned)c[1], P.u[0], P.u[2]);
        }
        {
          auto c = __builtin_amdgcn_permlane32_swap(xa1, xb1, false, false);
          plane16_swap((unsigned)c[0], (unsigned)c[1], P.u[1], P.u[3]);
        }
        pa_prev[ks2][mt] = P.v;
      }

    __syncthreads();   // reads of Ks[kb]/Vs[kb^1] done; K(g+1),V(g) gloads drained
  }

  // epilogue PV(last tile): V in Vs[(nt_-1)&1]
  {
    const int kb = (nt_ - 1) & 1;
#pragma unroll
    for (int ks2 = 0; ks2 < 2; ks2++) {
      f16x8 vb[8];
#pragma unroll
      for (int dt = 0; dt < 8; dt++)
        vb[dt] = *(const f16x8*)(&Vs[kb][(dt * 16 + l16) * 64 + (((ks2 * 4 + quad) ^ (l16 & 7))) * 8]);
#pragma unroll
      for (int mt = 0; mt < 2; mt++) {
#pragma unroll
        for (int dt = 0; dt < 8; dt++)
          Oa[mt][dt] = __builtin_amdgcn_mfma_f32_16x16x32_f16(pa_prev[ks2][mt], vb[dt], Oa[mt][dt], 0, 0, 0);
        lac[mt] = __builtin_amdgcn_mfma_f32_16x16x32_f16(pa_prev[ks2][mt], ones8, lac[mt], 0, 0, 0);
      }
    }
  }

  // epilogue: unnormalized O + row sums l (C-layout: row q, col d)
  const long rbase = ((long)s * B_ + b) * N_ + qt * 128;
#pragma unroll
  for (int mt = 0; mt < 2; mt++)
#pragma unroll
    for (int rg = 0; rg < 4; rg++) {
      int r = w * 32 + mt * 16 + quad * 4 + rg;
#pragma unroll
      for (int dt = 0; dt < 8; dt++)
        Op[(rbase + r) * C2_ + dt * 16 + l16] = (f16)Oa[mt][dt][rg];
      if (l16 == 0) ls[rbase + r] = lac[mt][rg];
    }
}

// ---------------------------------------------------------------------------
// conv2 v3: oh-MERGED — grid (8,64); each block stages Op/Bsw ONCE and runs
// both output-channel halves sequentially (saves 16 MB Op re-read + half the
// staging work chip-wide). Obuf is a SEPARATE LDS region (no Bsw alias -> Bsw
// survives for oh=1). LDS 70144 B -> 2 blocks/CU, 512 blocks = one full round.
// Epilogue per oh: acc -> Obuf -> float4-coalesced out/x (R10 pattern).
// ---------------------------------------------------------------------------
__global__ __launch_bounds__(256, 2)
void conv2_kernel(const f16* __restrict__ Op, const float* __restrict__ ls,
                  const f16* __restrict__ w2h,
                  const float* __restrict__ b2,
                  const float* __restrict__ scale,
                  const float* __restrict__ x,
                  float* __restrict__ out, int ns)
{
  __shared__ __align__(16) char smem2[70144];
  f16*   Or   = (f16*)smem2;                    // [128][72]        (18432 B)
  f16*   Bsw  = (f16*)(smem2 + 18432);          // [64][128] XOR-16 (16384 B)
  float* invL = (float*)(smem2 + 34816);        // [128]            (512 B)
  float* Obuf = (float*)(smem2 + 35328);        // [128][68]        (34816 B)

  const int t = threadIdx.x;
  const int w = t >> 6, lane = t & 63, quad = lane >> 4, l16 = lane & 15;
  const int b = blockIdx.x, pt = blockIdx.y;
  const long base0 = (long)b * 524288;            // batch offset within a split

  if (t < 128) {
    int q = t * 32 + (pt >> 1);
    float l = 0.f;
    for (int si = 0; si < ns; si++)
      l += ls[(long)si * 32768 + (long)b * N_ + q];
    invL[t] = 1.0f / fmaxf(l, 1e-20f);
  }
  __syncthreads();

#pragma unroll
  for (int pass = 0; pass < 4; pass++) {
    int j = (t >> 3) + pass * 32;            // 0..127
    int c8 = (t & 7) * 8;                    // p_local
    float fa[8] = {0.f,0.f,0.f,0.f,0.f,0.f,0.f,0.f};
    for (int si = 0; si < ns; si++) {
      f16x8 a = *(const f16x8*)(Op + (long)si * 4194304 + base0 + (long)j * N_ + pt * 64 + c8);
#pragma unroll
      for (int jj = 0; jj < 8; jj++) fa[jj] += (float)a[jj];
    }
    float iv = invL[j];
    f16x8 r;
#pragma unroll
    for (int jj = 0; jj < 8; jj++)
      r[jj] = (f16)(fa[jj] * iv);
    *(f16x8*)(&Or[j * 72 + c8]) = r;
  }
  __syncthreads();
#pragma unroll
  for (int pass = 0; pass < 4; pass++) {
    int p = t & 63;
    int q = (t >> 6) + pass * 4;             // j-block 0..15
    f16x8 vv;
#pragma unroll
    for (int jj = 0; jj < 8; jj++) vv[jj] = Or[(q * 8 + jj) * 72 + p];
    *(f16x8*)(&Bsw[p * 128 + ((q ^ (p & 15))) * 8]) = vv;
  }
  __syncthreads();

#pragma unroll 1
  for (int oh = 0; oh < 2; oh++) {
    f32x4 acc[2][4];
#pragma unroll
    for (int i = 0; i < 2; i++)
#pragma unroll
      for (int j = 0; j < 4; j++) acc[i][j] = (f32x4){0.f, 0.f, 0.f, 0.f};

#pragma unroll
    for (int ks = 0; ks < 4; ks++) {
      f16x8 bfr[4];
#pragma unroll
      for (int nt = 0; nt < 4; nt++)
        bfr[nt] = *(const f16x8*)(&Bsw[(nt * 16 + l16) * 128 + (((ks * 4 + quad) ^ l16)) * 8]);
#pragma unroll
      for (int mt = 0; mt < 2; mt++) {
        int o = oh * 128 + w * 32 + mt * 16 + l16;
        f16x8 ah = *(const f16x8*)(w2h + o * C2_ + ks * 32 + quad * 8);
#pragma unroll
        for (int nt = 0; nt < 4; nt++)
          acc[mt][nt] = __builtin_amdgcn_mfma_f32_16x16x32_f16(ah, bfr[nt], acc[mt][nt], 0, 0, 0);
      }
    }

    __syncthreads();   // oh=1: prior Obuf reads done before overwrite
#pragma unroll
    for (int mt = 0; mt < 2; mt++)
#pragma unroll
      for (int nt = 0; nt < 4; nt++)
#pragma unroll
        for (int rg = 0; rg < 4; rg++)
          Obuf[(w * 32 + mt * 16 + quad * 4 + rg) * 68 + nt * 16 + l16] = acc[mt][nt][rg];
    __syncthreads();
#pragma unroll
    for (int pass = 0; pass < 8; pass++) {
      int idx = pass * 256 + t;          // 0..2047 float4 slots
      int ol  = idx >> 4;                // 0..127
      int p4  = (idx & 15) * 4;          // 0..60
      float4 v = *(const float4*)(&Obuf[ol * 68 + p4]);
      int o = oh * 128 + ol;
      float so = scale[o], bo = b2[o];
      long xo = ((long)b * C_ + o) * N_ + pt * 64 + p4;
      float4 xv = *(const float4*)(x + xo);
      float4 r;
      r.x = (v.x + bo) * so + xv.x;
      r.y = (v.y + bo) * so + xv.y;
      r.z = (v.z + bo) * so + xv.z;
      r.w = (v.w + bo) * so + xv.w;
      *(float4*)(out + xo) = r;
    }
  }
}

extern "C" void kernel_launch(void* const* d_in, const int* in_sizes, int n_in,
                              void* d_out, int out_size, void* d_ws, size_t ws_size,
                              hipStream_t stream) {
  const float* x     = (const float*)d_in[0];
  const float* W1    = (const float*)d_in[1];
  const float* b1    = (const float*)d_in[2];
  const float* W2    = (const float*)d_in[3];
  const float* b2    = (const float*)d_in[4];
  const float* scale = (const float*)d_in[5];
  float* outp = (float*)d_out;

  const size_t NE = (size_t)B_ * N_ * C2_;       // 4,194,304
  const int ns = 2;   // residency is VGPR-capped at 2 WG/CU; ns>2 only adds Op traffic (R5)

  f16* Y   = (f16*)d_ws;                         // 8 MiB
  f16* Yt  = Y + NE;                             // 8 MiB
  f16* Op  = Yt + NE;                            // ns x 8 MiB (unnormalized)
  float* ls = (float*)(Op + (size_t)ns * NE);    // ns x 32768 f32 row sums
  f16* w1h = (f16*)(ls + (size_t)ns * 32768);
  f16* w2h = w1h + 32768;

  prep_kernel <<<dim3(128),       dim3(256), 0, stream>>>(W1, W2, w1h, w2h);
  conv1_kernel<<<dim3(8, 128),    dim3(256), 0, stream>>>(x, w1h, b1, Y, Yt);
  attn_kernel <<<dim3(8, 32, ns), dim3(256), 0, stream>>>(Y, Yt, Op, ls);
  conv2_kernel<<<dim3(8, 64),     dim3(256), 0, stream>>>(Op, ls, w2h, b2, scale, x, outp, ns);
}